// Round 2
// baseline (524.217 us; speedup 1.0000x reference)
//
#include <hip/hip_runtime.h>
#include <hip/hip_bf16.h>
#include <stdint.h>

// XCA (cross-covariance attention), B=8 N=8192 C=384 H=8 Dh=48.
// Input dtype (bf16 vs f32) detected at runtime by k_probe -> flag in ws.
//  k_probe     : sniff low-16-bit bf16 exponent sanity of x -> flag (1=bf16, 0=f32)
//  k_zero      : zero S/ssq accumulators (ws re-poisoned 0xAA each call)
//  k_gemm_qkv  : x @ w_qkv^T (MFMA 128x128 tile, register-staged LDS);
//                q,k stored (BH,Dh,N), v stored (B,N,C) -- all bf16 in ws
//  k_gram      : per (b,h): S=Q K^T over n (MFMA) + row sumsq, atomicAdd partials
//  k_softmax   : attn = softmax(S[d][e]/(|q_d||k_e|))   (fp32)
//  k_weff      : Weff_b[c'][h*48+e] = sum_d Wp[c'][h*48+d] attn[b,h,d,e]
//  k_gemm_out  : out[b,n,c'] = sum_c Weff_b[c'][c] V[b,n,c] + bias  (MFMA)

typedef __bf16 bf16_t;
typedef __attribute__((ext_vector_type(8))) __bf16 bf16x8;
typedef __attribute__((ext_vector_type(4))) float f32x4;

#define NTOK 8192
#define CDIM 384
#define WH   25165824   // 8*8*48*8192 elements per q/k plane
#define DHN  393216     // 48*8192

__device__ __forceinline__ f32x4 mfma16(bf16x8 a, bf16x8 b, f32x4 c) {
  return __builtin_amdgcn_mfma_f32_16x16x32_bf16(a, b, c, 0, 0, 0);
}

template <bool BF16>
__device__ __forceinline__ bf16x8 load8(const void* p, int idx) {
  if constexpr (BF16) {
    return *(const bf16x8*)((const bf16_t*)p + idx);
  } else {
    const float* f = (const float*)p + idx;
    f32x4 a = *(const f32x4*)f;
    f32x4 b = *(const f32x4*)(f + 4);
    bf16x8 r;
    r[0] = (bf16_t)a[0]; r[1] = (bf16_t)a[1]; r[2] = (bf16_t)a[2]; r[3] = (bf16_t)a[3];
    r[4] = (bf16_t)b[0]; r[5] = (bf16_t)b[1]; r[6] = (bf16_t)b[2]; r[7] = (bf16_t)b[3];
    return r;
  }
}

// ---------------- probe: are inputs bf16 (1) or f32 (0)? ----------------
__global__ void k_probe(const uint32_t* __restrict__ X, int* __restrict__ flag) {
  __shared__ int cnt;
  if (threadIdx.x == 0) cnt = 0;
  __syncthreads();
  const uint32_t w = X[threadIdx.x];
  const int e = (int)((w >> 7) & 0xFF);  // exponent of low-16 as bf16
  const int sane = (e >= 110 && e <= 131) ? 1 : 0;  // |v| in ~[2^-17, 32)
  atomicAdd(&cnt, sane);
  __syncthreads();
  if (threadIdx.x == 0) *flag = (cnt >= 128) ? 1 : 0;
}

// ---------------- zero fp32 accumulators ----------------
__global__ void k_zero(float* __restrict__ p, int n) {
  int i = blockIdx.x * 256 + threadIdx.x;
  if (i < n) p[i] = 0.f;
}

// ---------------- K1: qkv = x @ w_qkv^T ----------------
// A = w_qkv (1152 x 384 rows j), B = x (65536 x 384 rows m). D[j][m].
// grid (9 j-tiles, 512 m-tiles): j-tiles adjacent so each x-tile stays in L2.
template <bool BF16>
__device__ __forceinline__ void gemm_qkv_body(const void* __restrict__ X,
                                              const void* __restrict__ Wqkv,
                                              bf16_t* __restrict__ qkv,
                                              bf16_t* As, bf16_t* Bs) {
  const int tid = threadIdx.x;
  const int lane = tid & 63;
  const int wr = tid >> 7, wc = (tid >> 6) & 1;
  const int q4 = lane >> 4, l16 = lane & 15;
  const int jt = blockIdx.x;
  const int rowA0 = jt * 128;
  const int rowB0 = blockIdx.y * 128;

  f32x4 acc[4][4];
#pragma unroll
  for (int i = 0; i < 4; i++)
#pragma unroll
    for (int j = 0; j < 4; j++) acc[i][j] = (f32x4){0.f, 0.f, 0.f, 0.f};

  const int r0 = tid >> 2, kk = (tid & 3) << 3;  // chunk tid -> row r0, k-off kk

  for (int k0 = 0; k0 < CDIM; k0 += 32) {
    bf16x8 a0 = load8<BF16>(Wqkv, (rowA0 + r0) * CDIM + k0 + kk);
    bf16x8 a1 = load8<BF16>(Wqkv, (rowA0 + r0 + 64) * CDIM + k0 + kk);
    bf16x8 b0 = load8<BF16>(X, (rowB0 + r0) * CDIM + k0 + kk);
    bf16x8 b1 = load8<BF16>(X, (rowB0 + r0 + 64) * CDIM + k0 + kk);
    __syncthreads();  // prior iteration's LDS reads complete
    *(bf16x8*)&As[tid * 8] = a0;
    *(bf16x8*)&As[(tid + 256) * 8] = a1;
    *(bf16x8*)&Bs[tid * 8] = b0;
    *(bf16x8*)&Bs[(tid + 256) * 8] = b1;
    __syncthreads();
    bf16x8 af[4], bfr[4];
#pragma unroll
    for (int i = 0; i < 4; i++) {
      af[i]  = *(const bf16x8*)&As[(wr * 64 + i * 16 + l16) * 32 + q4 * 8];
      bfr[i] = *(const bf16x8*)&Bs[(wc * 64 + i * 16 + l16) * 32 + q4 * 8];
    }
#pragma unroll
    for (int i = 0; i < 4; i++)
#pragma unroll
      for (int j = 0; j < 4; j++) acc[i][j] = mfma16(af[i], bfr[j], acc[i][j]);
  }

  const int which = jt / 3;  // 0=q 1=k 2=v (uniform per block: 3 tiles each)
#pragma unroll
  for (int i = 0; i < 4; i++) {
#pragma unroll
    for (int j = 0; j < 4; j++) {
      const int mg = rowB0 + wc * 64 + j * 16 + l16;
#pragma unroll
      for (int r = 0; r < 4; r++) {
        const int jg = rowA0 + wr * 64 + i * 16 + q4 * 4 + r;
        const int rin = jg - which * 384;
        int addr;
        if (which < 2) {
          const int h = rin / 48, dh = rin - h * 48;
          addr = which * WH + (((mg >> 13) << 3) + h) * DHN + dh * NTOK + (mg & 8191);
        } else {
          addr = 2 * WH + mg * CDIM + rin;
        }
        qkv[addr] = (bf16_t)acc[i][j][r];
      }
    }
  }
}

__global__ __launch_bounds__(256, 2) void k_gemm_qkv(
    const void* __restrict__ X, const void* __restrict__ Wqkv,
    bf16_t* __restrict__ qkv, const int* __restrict__ flagp) {
  __shared__ __align__(16) bf16_t As[128 * 32];
  __shared__ __align__(16) bf16_t Bs[128 * 32];
  if (*flagp) gemm_qkv_body<true>(X, Wqkv, qkv, As, Bs);
  else        gemm_qkv_body<false>(X, Wqkv, qkv, As, Bs);
}

// ---------------- K2: Gram S=Q K^T + sumsq ----------------
// grid (8 n-splits, 64 bh). LDS tiles: 4 subtiles [48][32] bf16.
__global__ __launch_bounds__(256, 2) void k_gram(
    const bf16_t* __restrict__ qkv, float* __restrict__ S_acc, float* __restrict__ ssq_acc) {
  __shared__ __align__(16) float sm[9312];  // 37,248 B
  bf16_t* Qs = (bf16_t*)sm;                 // 6144 bf16 = [4][48][32]
  bf16_t* Ks = Qs + 6144;
  float* ssq_sm = sm + 9216;                // 96 floats

  const int tid = threadIdx.x;
  const int wave = tid >> 6, lane = tid & 63, q4 = lane >> 4, l16 = lane & 15;
  const int s = blockIdx.x, bh = blockIdx.y;
  const bf16_t* Qg = qkv + bh * DHN;
  const bf16_t* Kg = qkv + WH + bh * DHN;

  if (tid < 96) ssq_sm[tid] = 0.f;

  f32x4 acc[3][3];
#pragma unroll
  for (int i = 0; i < 3; i++)
#pragma unroll
    for (int j = 0; j < 3; j++) acc[i][j] = (f32x4){0.f, 0.f, 0.f, 0.f};
  float qss[3] = {0.f, 0.f, 0.f}, kss[3] = {0.f, 0.f, 0.f};

  for (int t0 = 0; t0 < 8; t0++) {
    const int n0 = s * 1024 + t0 * 128;
    bf16x8 qv[3], kv[3];
#pragma unroll
    for (int jj = 0; jj < 3; jj++) {
      const int c = jj * 256 + tid;                 // 768 chunks per tile
      const int st = c / 192, rem = c - st * 192;   // subtile, then [48][32]
      const int row = rem >> 2, kk = (rem & 3) << 3;
      const int gofs = row * NTOK + n0 + st * 32 + kk;
      qv[jj] = *(const bf16x8*)(Qg + gofs);
      kv[jj] = *(const bf16x8*)(Kg + gofs);
    }
    __syncthreads();  // prior iteration's LDS reads complete
#pragma unroll
    for (int jj = 0; jj < 3; jj++) {
      *(bf16x8*)&Qs[(jj * 256 + tid) * 8] = qv[jj];
      *(bf16x8*)&Ks[(jj * 256 + tid) * 8] = kv[jj];
    }
    __syncthreads();
    bf16x8 qf[3], kf[3];
#pragma unroll
    for (int i = 0; i < 3; i++) {
      qf[i] = *(const bf16x8*)&Qs[wave * 1536 + (i * 16 + l16) * 32 + q4 * 8];
      kf[i] = *(const bf16x8*)&Ks[wave * 1536 + (i * 16 + l16) * 32 + q4 * 8];
    }
#pragma unroll
    for (int i = 0; i < 3; i++) {
#pragma unroll
      for (int u = 0; u < 8; u++) {
        const float qv2 = (float)qf[i][u], kv2 = (float)kf[i][u];
        qss[i] += qv2 * qv2;
        kss[i] += kv2 * kv2;
      }
#pragma unroll
      for (int j = 0; j < 3; j++) acc[i][j] = mfma16(qf[i], kf[j], acc[i][j]);
    }
  }

  __syncthreads();  // all LDS reads done before overwriting as reduction scratch
  float* red = sm;  // 4 waves x 2304 fp32
#pragma unroll
  for (int i = 0; i < 3; i++)
#pragma unroll
    for (int j = 0; j < 3; j++)
#pragma unroll
      for (int r = 0; r < 4; r++)
        red[wave * 2304 + (i * 3 + j) * 256 + lane * 4 + r] = acc[i][j][r];
#pragma unroll
  for (int i = 0; i < 3; i++) {
    atomicAdd(&ssq_sm[i * 16 + l16], qss[i]);
    atomicAdd(&ssq_sm[48 + i * 16 + l16], kss[i]);
  }
  __syncthreads();
  for (int idx = tid; idx < 2304; idx += 256) {
    const float v = red[idx] + red[2304 + idx] + red[4608 + idx] + red[6912 + idx];
    const int tile = idx >> 8, ln = (idx >> 2) & 63, r = idx & 3;
    const int i = tile / 3, j = tile - i * 3;
    const int d = i * 16 + ((ln >> 4) << 2) + r;
    const int e = j * 16 + (ln & 15);
    atomicAdd(&S_acc[bh * 2304 + d * 48 + e], v);
  }
  if (tid < 96) atomicAdd(&ssq_acc[bh * 96 + tid], ssq_sm[tid]);
}

// ---------------- K3: softmax(S / (|q_d||k_e|)) ----------------
__global__ void k_softmax(const float* __restrict__ S_acc, const float* __restrict__ ssq_acc,
                          float* __restrict__ attn_f) {
  __shared__ float invk_sm[48];
  const int bh = blockIdx.x, d = threadIdx.x;
  if (d < 48) invk_sm[d] = 1.f / fmaxf(sqrtf(ssq_acc[bh * 96 + 48 + d]), 1e-12f);
  __syncthreads();
  if (d < 48) {
    const float invq = 1.f / fmaxf(sqrtf(ssq_acc[bh * 96 + d]), 1e-12f);
    float lg[48], mx = -1e30f;
#pragma unroll
    for (int e = 0; e < 48; e++) {
      lg[e] = S_acc[bh * 2304 + d * 48 + e] * invq * invk_sm[e];
      mx = fmaxf(mx, lg[e]);
    }
    float ssum = 0.f;
#pragma unroll
    for (int e = 0; e < 48; e++) { lg[e] = expf(lg[e] - mx); ssum += lg[e]; }
    const float inv = 1.f / ssum;
#pragma unroll
    for (int e = 0; e < 48; e++) attn_f[bh * 2304 + d * 48 + e] = lg[e] * inv;
  }
}

// ---------------- K4: Weff_b[c'][h*48+e] = sum_d Wp[c'][h*48+d] attn[bh][d][e] ------
__global__ __launch_bounds__(256, 2) void k_weff(
    const float* __restrict__ attn_f, const void* __restrict__ Wp,
    bf16_t* __restrict__ Weff, const int* __restrict__ flagp) {
  __shared__ float attn_sm[2304];
  const int isb = *flagp;
  const int b = blockIdx.x >> 3, h = blockIdx.x & 7;
  const int tid = threadIdx.x, bh = b * 8 + h;
  for (int i = tid; i < 2304; i += 256) attn_sm[i] = attn_f[bh * 2304 + i];
  __syncthreads();
  const int cb = tid >> 3, eb = tid & 7;  // 32 c'-groups of 12, 8 e-groups of 6
  float res[12][6];
#pragma unroll
  for (int u = 0; u < 12; u++)
#pragma unroll
    for (int v = 0; v < 6; v++) res[u][v] = 0.f;

  for (int d8 = 0; d8 < 6; d8++) {
    bf16x8 wv[12];
#pragma unroll
    for (int u = 0; u < 12; u++) {
      const int idx = (cb * 12 + u) * CDIM + h * 48 + d8 * 8;
      wv[u] = isb ? load8<true>(Wp, idx) : load8<false>(Wp, idx);
    }
#pragma unroll
    for (int dd = 0; dd < 8; dd++) {
      float wf[12];
#pragma unroll
      for (int u = 0; u < 12; u++) wf[u] = (float)wv[u][dd];
      const int d = d8 * 8 + dd;
#pragma unroll
      for (int v = 0; v < 6; v++) {
        const float a = attn_sm[d * 48 + eb * 6 + v];
#pragma unroll
        for (int u = 0; u < 12; u++) res[u][v] += wf[u] * a;
      }
    }
  }
#pragma unroll
  for (int u = 0; u < 12; u++)
#pragma unroll
    for (int v = 0; v < 6; v++)
      Weff[b * 147456 + (cb * 12 + u) * CDIM + h * 48 + eb * 6 + v] = (bf16_t)res[u][v];
}

// ---------------- K5: out[b,n,c'] = sum_c Weff_b[c'][c] V[b,n,c] + bias[c'] --------
__global__ __launch_bounds__(256, 2) void k_gemm_out(
    const bf16_t* __restrict__ Weff, const bf16_t* __restrict__ qkv,
    const void* __restrict__ bias, void* __restrict__ out, const int* __restrict__ flagp) {
  __shared__ __align__(16) bf16_t As[128 * 32];
  __shared__ __align__(16) bf16_t Bs[128 * 32];
  const int isb = *flagp;
  const int tid = threadIdx.x;
  const int lane = tid & 63;
  const int wr = tid >> 7, wc = (tid >> 6) & 1;
  const int q4 = lane >> 4, l16 = lane & 15;
  const int b = blockIdx.z;
  const int rowA0 = blockIdx.y * 128;  // c' tile (0..2)
  const int rowB0 = blockIdx.x * 128;  // n tile (0..63)
  const bf16_t* Abase = Weff + b * 147456;
  const bf16_t* Bbase = qkv + 2 * WH + b * (NTOK * CDIM);

  f32x4 acc[4][4];
#pragma unroll
  for (int i = 0; i < 4; i++)
#pragma unroll
    for (int j = 0; j < 4; j++) acc[i][j] = (f32x4){0.f, 0.f, 0.f, 0.f};

  const int r0 = tid >> 2, kk = (tid & 3) << 3;
  for (int k0 = 0; k0 < CDIM; k0 += 32) {
    bf16x8 a0 = *(const bf16x8*)(Abase + (rowA0 + r0) * CDIM + k0 + kk);
    bf16x8 a1 = *(const bf16x8*)(Abase + (rowA0 + r0 + 64) * CDIM + k0 + kk);
    bf16x8 b0 = *(const bf16x8*)(Bbase + (rowB0 + r0) * CDIM + k0 + kk);
    bf16x8 b1 = *(const bf16x8*)(Bbase + (rowB0 + r0 + 64) * CDIM + k0 + kk);
    __syncthreads();
    *(bf16x8*)&As[tid * 8] = a0;
    *(bf16x8*)&As[(tid + 256) * 8] = a1;
    *(bf16x8*)&Bs[tid * 8] = b0;
    *(bf16x8*)&Bs[(tid + 256) * 8] = b1;
    __syncthreads();
    bf16x8 af[4], bfr[4];
#pragma unroll
    for (int i = 0; i < 4; i++) {
      af[i]  = *(const bf16x8*)&As[(wr * 64 + i * 16 + l16) * 32 + q4 * 8];
      bfr[i] = *(const bf16x8*)&Bs[(wc * 64 + i * 16 + l16) * 32 + q4 * 8];
    }
#pragma unroll
    for (int i = 0; i < 4; i++)
#pragma unroll
      for (int j = 0; j < 4; j++) acc[i][j] = mfma16(af[i], bfr[j], acc[i][j]);
  }

#pragma unroll
  for (int i = 0; i < 4; i++) {
#pragma unroll
    for (int j = 0; j < 4; j++) {
      const int ng = rowB0 + wc * 64 + j * 16 + l16;
#pragma unroll
      for (int r = 0; r < 4; r++) {
        const int cg = rowA0 + wr * 64 + i * 16 + q4 * 4 + r;
        const float bv = isb ? (float)((const bf16_t*)bias)[cg] : ((const float*)bias)[cg];
        const float v = acc[i][j][r] + bv;
        const int oi = (b * NTOK + ng) * CDIM + cg;
        if (isb) ((bf16_t*)out)[oi] = (bf16_t)v;
        else     ((float*)out)[oi] = v;
      }
    }
  }
}

extern "C" void kernel_launch(void* const* d_in, const int* in_sizes, int n_in,
                              void* d_out, int out_size, void* d_ws, size_t ws_size,
                              hipStream_t stream) {
  (void)in_sizes; (void)n_in; (void)out_size; (void)ws_size;
  const void* X    = d_in[0];
  const void* Wqkv = d_in[1];
  const void* Wp   = d_in[2];
  const void* bias = d_in[3];

  char* ws = (char*)d_ws;
  bf16_t* qkv    = (bf16_t*)ws;                     // 3*WH bf16 = 150,994,944 B
  float*  S_acc  = (float*)(ws + 150994944);        // 64*2304 f32
  float*  ssq    = (float*)(ws + 151584768);        // 64*96 f32
  float*  attn_f = (float*)(ws + 151609344);        // 64*2304 f32
  bf16_t* Weff   = (bf16_t*)(ws + 152199168);       // 8*384*384 bf16
  int*    flag   = (int*)(ws + 154558464);

  k_probe<<<dim3(1), 256, 0, stream>>>((const uint32_t*)X, flag);
  k_zero<<<dim3(600), 256, 0, stream>>>(S_acc, 153600);  // S_acc + ssq contiguous
  k_gemm_qkv<<<dim3(9, 512), 256, 0, stream>>>(X, Wqkv, qkv, flag);
  k_gram<<<dim3(8, 64), 256, 0, stream>>>(qkv, S_acc, ssq);
  k_softmax<<<dim3(64), 64, 0, stream>>>(S_acc, ssq, attn_f);
  k_weff<<<dim3(64), 256, 0, stream>>>(attn_f, Wp, Weff, flag);
  k_gemm_out<<<dim3(64, 3, 8), 256, 0, stream>>>(Weff, qkv, bias, d_out, flag);
}

// Round 3
// 492.415 us; speedup vs baseline: 1.0646x; 1.0646x over previous
//
#include <hip/hip_runtime.h>
#include <hip/hip_bf16.h>
#include <stdint.h>

// XCA (cross-covariance attention), B=8 N=8192 C=384 H=8 Dh=48.
// R3: reuse-loop moved inside blocks to kill 10x HBM over-fetch seen in R2.
//  k_probe     : sniff dtype of x -> flag (1=bf16, 0=f32)  [R2 counters say bf16]
//  k_zero      : zero S/ssq accumulators
//  k_gemm_qkv  : 512 m-tile blocks, loop jt=0..8 inside (x-tile L2-resident);
//                q,k stored (BH,Dh,N), v stored (B,N,C)
//  k_gram      : per (b,h): S=Q K^T over n (MFMA) + row sumsq, atomicAdd partials
//  k_softmax   : attn = softmax(S[d][e]/(|q_d||k_e|))
//  k_weff      : Weff_b[c'][h*48+e] = sum_d Wp[c'][h*48+d] attn[b,h,d,e]
//  k_gemm_out  : grid (64 nt, 8 b), loop ct=0..2 inside (V-tile fetched once)

typedef __bf16 bf16_t;
typedef __attribute__((ext_vector_type(8))) __bf16 bf16x8;
typedef __attribute__((ext_vector_type(4))) float f32x4;

#define NTOK 8192
#define CDIM 384
#define WH   25165824   // 8*8*48*8192 elements per q/k plane
#define DHN  393216     // 48*8192

__device__ __forceinline__ f32x4 mfma16(bf16x8 a, bf16x8 b, f32x4 c) {
  return __builtin_amdgcn_mfma_f32_16x16x32_bf16(a, b, c, 0, 0, 0);
}

template <bool BF16>
__device__ __forceinline__ bf16x8 load8(const void* p, int idx) {
  if constexpr (BF16) {
    return *(const bf16x8*)((const bf16_t*)p + idx);
  } else {
    const float* f = (const float*)p + idx;
    f32x4 a = *(const f32x4*)f;
    f32x4 b = *(const f32x4*)(f + 4);
    bf16x8 r;
    r[0] = (bf16_t)a[0]; r[1] = (bf16_t)a[1]; r[2] = (bf16_t)a[2]; r[3] = (bf16_t)a[3];
    r[4] = (bf16_t)b[0]; r[5] = (bf16_t)b[1]; r[6] = (bf16_t)b[2]; r[7] = (bf16_t)b[3];
    return r;
  }
}

// ---------------- probe: are inputs bf16 (1) or f32 (0)? ----------------
__global__ void k_probe(const uint32_t* __restrict__ X, int* __restrict__ flag) {
  __shared__ int cnt;
  if (threadIdx.x == 0) cnt = 0;
  __syncthreads();
  const uint32_t w = X[threadIdx.x];
  const int e = (int)((w >> 7) & 0xFF);  // exponent of low-16 as bf16
  const int sane = (e >= 110 && e <= 131) ? 1 : 0;
  atomicAdd(&cnt, sane);
  __syncthreads();
  if (threadIdx.x == 0) *flag = (cnt >= 128) ? 1 : 0;
}

// ---------------- zero fp32 accumulators ----------------
__global__ void k_zero(float* __restrict__ p, int n) {
  int i = blockIdx.x * 256 + threadIdx.x;
  if (i < n) p[i] = 0.f;
}

// ---------------- K1: qkv = x @ w_qkv^T ----------------
// A = w_qkv (1152x384 rows j), B = x (65536x384 rows m). D[j][m].
// Grid: 512 m-tiles (= exactly 2 blocks/CU, no tail). jt loop inside the block:
// the 98 KB x-tile is re-read from the same XCD's L2 (8x), not from HBM (R2: 526 MB fetch).
template <bool BF16>
__device__ __forceinline__ void gemm_qkv_body(const void* __restrict__ X,
                                              const void* __restrict__ Wqkv,
                                              bf16_t* __restrict__ qkv,
                                              bf16_t* As, bf16_t* Bs) {
  const int tid = threadIdx.x;
  const int lane = tid & 63;
  const int wr = tid >> 7, wc = (tid >> 6) & 1;
  const int q4 = lane >> 4, l16 = lane & 15;
  const int rowB0 = blockIdx.x * 128;
  const int r0 = tid >> 2, kk = (tid & 3) << 3;

  for (int jt = 0; jt < 9; jt++) {
    const int rowA0 = jt * 128;
    f32x4 acc[4][4];
#pragma unroll
    for (int i = 0; i < 4; i++)
#pragma unroll
      for (int j = 0; j < 4; j++) acc[i][j] = (f32x4){0.f, 0.f, 0.f, 0.f};

    for (int k0 = 0; k0 < CDIM; k0 += 32) {
      bf16x8 a0 = load8<BF16>(Wqkv, (rowA0 + r0) * CDIM + k0 + kk);
      bf16x8 a1 = load8<BF16>(Wqkv, (rowA0 + r0 + 64) * CDIM + k0 + kk);
      bf16x8 b0 = load8<BF16>(X, (rowB0 + r0) * CDIM + k0 + kk);
      bf16x8 b1 = load8<BF16>(X, (rowB0 + r0 + 64) * CDIM + k0 + kk);
      __syncthreads();  // prior iteration's LDS frag reads complete
      *(bf16x8*)&As[tid * 8] = a0;
      *(bf16x8*)&As[(tid + 256) * 8] = a1;
      *(bf16x8*)&Bs[tid * 8] = b0;
      *(bf16x8*)&Bs[(tid + 256) * 8] = b1;
      __syncthreads();
      bf16x8 af[4], bfr[4];
#pragma unroll
      for (int i = 0; i < 4; i++) {
        af[i]  = *(const bf16x8*)&As[(wr * 64 + i * 16 + l16) * 32 + q4 * 8];
        bfr[i] = *(const bf16x8*)&Bs[(wc * 64 + i * 16 + l16) * 32 + q4 * 8];
      }
#pragma unroll
      for (int i = 0; i < 4; i++)
#pragma unroll
        for (int j = 0; j < 4; j++) acc[i][j] = mfma16(af[i], bfr[j], acc[i][j]);
    }

    const int which = jt / 3;  // 0=q 1=k 2=v (scalar-uniform per jt)
#pragma unroll
    for (int i = 0; i < 4; i++) {
#pragma unroll
      for (int j = 0; j < 4; j++) {
        const int mg = rowB0 + wc * 64 + j * 16 + l16;
#pragma unroll
        for (int r = 0; r < 4; r++) {
          const int jg = rowA0 + wr * 64 + i * 16 + q4 * 4 + r;
          const int rin = jg - which * 384;
          int addr;
          if (which < 2) {
            const int h = rin / 48, dh = rin - h * 48;
            addr = which * WH + (((mg >> 13) << 3) + h) * DHN + dh * NTOK + (mg & 8191);
          } else {
            addr = 2 * WH + mg * CDIM + rin;
          }
          qkv[addr] = (bf16_t)acc[i][j][r];
        }
      }
    }
  }
}

__global__ __launch_bounds__(256, 2) void k_gemm_qkv(
    const void* __restrict__ X, const void* __restrict__ Wqkv,
    bf16_t* __restrict__ qkv, const int* __restrict__ flagp) {
  __shared__ __align__(16) bf16_t As[128 * 32];
  __shared__ __align__(16) bf16_t Bs[128 * 32];
  if (*flagp) gemm_qkv_body<true>(X, Wqkv, qkv, As, Bs);
  else        gemm_qkv_body<false>(X, Wqkv, qkv, As, Bs);
}

// ---------------- K2: Gram S=Q K^T + sumsq ----------------
__global__ __launch_bounds__(256, 2) void k_gram(
    const bf16_t* __restrict__ qkv, float* __restrict__ S_acc, float* __restrict__ ssq_acc) {
  __shared__ __align__(16) float sm[9312];  // 37,248 B
  bf16_t* Qs = (bf16_t*)sm;                 // 6144 bf16 = [4][48][32]
  bf16_t* Ks = Qs + 6144;
  float* ssq_sm = sm + 9216;                // 96 floats

  const int tid = threadIdx.x;
  const int wave = tid >> 6, lane = tid & 63, q4 = lane >> 4, l16 = lane & 15;
  const int s = blockIdx.x, bh = blockIdx.y;
  const bf16_t* Qg = qkv + bh * DHN;
  const bf16_t* Kg = qkv + WH + bh * DHN;

  if (tid < 96) ssq_sm[tid] = 0.f;

  f32x4 acc[3][3];
#pragma unroll
  for (int i = 0; i < 3; i++)
#pragma unroll
    for (int j = 0; j < 3; j++) acc[i][j] = (f32x4){0.f, 0.f, 0.f, 0.f};
  float qss[3] = {0.f, 0.f, 0.f}, kss[3] = {0.f, 0.f, 0.f};

  for (int t0 = 0; t0 < 8; t0++) {
    const int n0 = s * 1024 + t0 * 128;
    bf16x8 qv[3], kv[3];
#pragma unroll
    for (int jj = 0; jj < 3; jj++) {
      const int c = jj * 256 + tid;
      const int st = c / 192, rem = c - st * 192;
      const int row = rem >> 2, kk = (rem & 3) << 3;
      const int gofs = row * NTOK + n0 + st * 32 + kk;
      qv[jj] = *(const bf16x8*)(Qg + gofs);
      kv[jj] = *(const bf16x8*)(Kg + gofs);
    }
    __syncthreads();
#pragma unroll
    for (int jj = 0; jj < 3; jj++) {
      *(bf16x8*)&Qs[(jj * 256 + tid) * 8] = qv[jj];
      *(bf16x8*)&Ks[(jj * 256 + tid) * 8] = kv[jj];
    }
    __syncthreads();
    bf16x8 qf[3], kf[3];
#pragma unroll
    for (int i = 0; i < 3; i++) {
      qf[i] = *(const bf16x8*)&Qs[wave * 1536 + (i * 16 + l16) * 32 + q4 * 8];
      kf[i] = *(const bf16x8*)&Ks[wave * 1536 + (i * 16 + l16) * 32 + q4 * 8];
    }
#pragma unroll
    for (int i = 0; i < 3; i++) {
#pragma unroll
      for (int u = 0; u < 8; u++) {
        const float qv2 = (float)qf[i][u], kv2 = (float)kf[i][u];
        qss[i] += qv2 * qv2;
        kss[i] += kv2 * kv2;
      }
#pragma unroll
      for (int j = 0; j < 3; j++) acc[i][j] = mfma16(qf[i], kf[j], acc[i][j]);
    }
  }

  __syncthreads();
  float* red = sm;  // 4 waves x 2304 fp32
#pragma unroll
  for (int i = 0; i < 3; i++)
#pragma unroll
    for (int j = 0; j < 3; j++)
#pragma unroll
      for (int r = 0; r < 4; r++)
        red[wave * 2304 + (i * 3 + j) * 256 + lane * 4 + r] = acc[i][j][r];
#pragma unroll
  for (int i = 0; i < 3; i++) {
    atomicAdd(&ssq_sm[i * 16 + l16], qss[i]);
    atomicAdd(&ssq_sm[48 + i * 16 + l16], kss[i]);
  }
  __syncthreads();
  for (int idx = tid; idx < 2304; idx += 256) {
    const float v = red[idx] + red[2304 + idx] + red[4608 + idx] + red[6912 + idx];
    const int tile = idx >> 8, ln = (idx >> 2) & 63, r = idx & 3;
    const int i = tile / 3, j = tile - i * 3;
    const int d = i * 16 + ((ln >> 4) << 2) + r;
    const int e = j * 16 + (ln & 15);
    atomicAdd(&S_acc[bh * 2304 + d * 48 + e], v);
  }
  if (tid < 96) atomicAdd(&ssq_acc[bh * 96 + tid], ssq_sm[tid]);
}

// ---------------- K3: softmax(S / (|q_d||k_e|)) ----------------
__global__ void k_softmax(const float* __restrict__ S_acc, const float* __restrict__ ssq_acc,
                          float* __restrict__ attn_f) {
  __shared__ float invk_sm[48];
  const int bh = blockIdx.x, d = threadIdx.x;
  if (d < 48) invk_sm[d] = 1.f / fmaxf(sqrtf(ssq_acc[bh * 96 + 48 + d]), 1e-12f);
  __syncthreads();
  if (d < 48) {
    const float invq = 1.f / fmaxf(sqrtf(ssq_acc[bh * 96 + d]), 1e-12f);
    float lg[48], mx = -1e30f;
#pragma unroll
    for (int e = 0; e < 48; e++) {
      lg[e] = S_acc[bh * 2304 + d * 48 + e] * invq * invk_sm[e];
      mx = fmaxf(mx, lg[e]);
    }
    float ssum = 0.f;
#pragma unroll
    for (int e = 0; e < 48; e++) { lg[e] = expf(lg[e] - mx); ssum += lg[e]; }
    const float inv = 1.f / ssum;
#pragma unroll
    for (int e = 0; e < 48; e++) attn_f[bh * 2304 + d * 48 + e] = lg[e] * inv;
  }
}

// ---------------- K4: Weff_b[c'][h*48+e] = sum_d Wp[c'][h*48+d] attn[bh][d][e] ------
__global__ __launch_bounds__(256, 2) void k_weff(
    const float* __restrict__ attn_f, const void* __restrict__ Wp,
    bf16_t* __restrict__ Weff, const int* __restrict__ flagp) {
  __shared__ float attn_sm[2304];
  const int isb = *flagp;
  const int b = blockIdx.x >> 3, h = blockIdx.x & 7;
  const int tid = threadIdx.x, bh = b * 8 + h;
  for (int i = tid; i < 2304; i += 256) attn_sm[i] = attn_f[bh * 2304 + i];
  __syncthreads();
  const int cb = tid >> 3, eb = tid & 7;
  float res[12][6];
#pragma unroll
  for (int u = 0; u < 12; u++)
#pragma unroll
    for (int v = 0; v < 6; v++) res[u][v] = 0.f;

  for (int d8 = 0; d8 < 6; d8++) {
    bf16x8 wv[12];
#pragma unroll
    for (int u = 0; u < 12; u++) {
      const int idx = (cb * 12 + u) * CDIM + h * 48 + d8 * 8;
      wv[u] = isb ? load8<true>(Wp, idx) : load8<false>(Wp, idx);
    }
#pragma unroll
    for (int dd = 0; dd < 8; dd++) {
      float wf[12];
#pragma unroll
      for (int u = 0; u < 12; u++) wf[u] = (float)wv[u][dd];
      const int d = d8 * 8 + dd;
#pragma unroll
      for (int v = 0; v < 6; v++) {
        const float a = attn_sm[d * 48 + eb * 6 + v];
#pragma unroll
        for (int u = 0; u < 12; u++) res[u][v] += wf[u] * a;
      }
    }
  }
#pragma unroll
  for (int u = 0; u < 12; u++)
#pragma unroll
    for (int v = 0; v < 6; v++)
      Weff[b * 147456 + (cb * 12 + u) * CDIM + h * 48 + eb * 6 + v] = (bf16_t)res[u][v];
}

// ---------------- K5: out[b,n,c'] = sum_c Weff_b[c'][c] V[b,n,c] + bias[c'] --------
// Grid (64 n-tiles, 8 b); ct loop inside -> V-tile fetched from HBM once, reused via L2.
__global__ __launch_bounds__(256, 2) void k_gemm_out(
    const bf16_t* __restrict__ Weff, const bf16_t* __restrict__ qkv,
    const void* __restrict__ bias, void* __restrict__ out, const int* __restrict__ flagp) {
  __shared__ __align__(16) bf16_t As[128 * 32];
  __shared__ __align__(16) bf16_t Bs[128 * 32];
  const int isb = *flagp;
  const int tid = threadIdx.x;
  const int lane = tid & 63;
  const int wr = tid >> 7, wc = (tid >> 6) & 1;
  const int q4 = lane >> 4, l16 = lane & 15;
  const int b = blockIdx.y;
  const int rowB0 = blockIdx.x * 128;  // n tile
  const bf16_t* Abase = Weff + b * 147456;
  const bf16_t* Bbase = qkv + 2 * WH + b * (NTOK * CDIM);
  const int r0 = tid >> 2, kk = (tid & 3) << 3;

  for (int ct = 0; ct < 3; ct++) {
    const int rowA0 = ct * 128;
    f32x4 acc[4][4];
#pragma unroll
    for (int i = 0; i < 4; i++)
#pragma unroll
      for (int j = 0; j < 4; j++) acc[i][j] = (f32x4){0.f, 0.f, 0.f, 0.f};

    for (int k0 = 0; k0 < CDIM; k0 += 32) {
      bf16x8 a0 = *(const bf16x8*)(Abase + (rowA0 + r0) * CDIM + k0 + kk);
      bf16x8 a1 = *(const bf16x8*)(Abase + (rowA0 + r0 + 64) * CDIM + k0 + kk);
      bf16x8 b0 = *(const bf16x8*)(Bbase + (rowB0 + r0) * CDIM + k0 + kk);
      bf16x8 b1 = *(const bf16x8*)(Bbase + (rowB0 + r0 + 64) * CDIM + k0 + kk);
      __syncthreads();
      *(bf16x8*)&As[tid * 8] = a0;
      *(bf16x8*)&As[(tid + 256) * 8] = a1;
      *(bf16x8*)&Bs[tid * 8] = b0;
      *(bf16x8*)&Bs[(tid + 256) * 8] = b1;
      __syncthreads();
      bf16x8 af[4], bfr[4];
#pragma unroll
      for (int i = 0; i < 4; i++) {
        af[i]  = *(const bf16x8*)&As[(wr * 64 + i * 16 + l16) * 32 + q4 * 8];
        bfr[i] = *(const bf16x8*)&Bs[(wc * 64 + i * 16 + l16) * 32 + q4 * 8];
      }
#pragma unroll
      for (int i = 0; i < 4; i++)
#pragma unroll
        for (int j = 0; j < 4; j++) acc[i][j] = mfma16(af[i], bfr[j], acc[i][j]);
    }

#pragma unroll
    for (int i = 0; i < 4; i++) {
#pragma unroll
      for (int j = 0; j < 4; j++) {
        const int ng = rowB0 + wc * 64 + j * 16 + l16;
#pragma unroll
        for (int r = 0; r < 4; r++) {
          const int cg = rowA0 + wr * 64 + i * 16 + q4 * 4 + r;
          const float bv = isb ? (float)((const bf16_t*)bias)[cg] : ((const float*)bias)[cg];
          const float v = acc[i][j][r] + bv;
          const int oi = (b * NTOK + ng) * CDIM + cg;
          if (isb) ((bf16_t*)out)[oi] = (bf16_t)v;
          else     ((float*)out)[oi] = v;
        }
      }
    }
  }
}

extern "C" void kernel_launch(void* const* d_in, const int* in_sizes, int n_in,
                              void* d_out, int out_size, void* d_ws, size_t ws_size,
                              hipStream_t stream) {
  (void)in_sizes; (void)n_in; (void)out_size; (void)ws_size;
  const void* X    = d_in[0];
  const void* Wqkv = d_in[1];
  const void* Wp   = d_in[2];
  const void* bias = d_in[3];

  char* ws = (char*)d_ws;
  bf16_t* qkv    = (bf16_t*)ws;                     // 3*WH bf16 = 150,994,944 B
  float*  S_acc  = (float*)(ws + 150994944);        // 64*2304 f32
  float*  ssq    = (float*)(ws + 151584768);        // 64*96 f32
  float*  attn_f = (float*)(ws + 151609344);        // 64*2304 f32
  bf16_t* Weff   = (bf16_t*)(ws + 152199168);       // 8*384*384 bf16
  int*    flag   = (int*)(ws + 154558464);

  k_probe<<<dim3(1), 256, 0, stream>>>((const uint32_t*)X, flag);
  k_zero<<<dim3(600), 256, 0, stream>>>(S_acc, 153600);
  k_gemm_qkv<<<dim3(512), 256, 0, stream>>>(X, Wqkv, qkv, flag);
  k_gram<<<dim3(8, 64), 256, 0, stream>>>(qkv, S_acc, ssq);
  k_softmax<<<dim3(64), 64, 0, stream>>>(S_acc, ssq, attn_f);
  k_weff<<<dim3(64), 256, 0, stream>>>(attn_f, Wp, Weff, flag);
  k_gemm_out<<<dim3(64, 8), 256, 0, stream>>>(Weff, qkv, bias, d_out, flag);
}